// Round 3
// baseline (306.541 us; speedup 1.0000x reference)
//
#include <hip/hip_runtime.h>

typedef _Float16 f16x8 __attribute__((ext_vector_type(8)));
typedef _Float16 f16x2 __attribute__((ext_vector_type(2)));
typedef float    f32x4 __attribute__((ext_vector_type(4)));

#define MFMA(a, b, c) __builtin_amdgcn_mfma_f32_16x16x32_f16((a), (b), (c), 0, 0, 0)

// Canonical-layout diagnostic build:
//  layer1: per-thread fp32 VALU (provably correct), h1 -> LDS point-major slice
//  layer2: MFMA, A-frag k = quad*8+j read straight from slice; W2 packed with
//          the SAME trivial map (no absorbed permutation anywhere)
//  layer3: per-thread fp32 VALU from canonical h2 slice
__global__ __launch_bounds__(256, 1)
void DeformationCorrector_78967268704761_kernel(
        const float* __restrict__ F,
        const float* __restrict__ W1, const float* __restrict__ b1,
        const float* __restrict__ W2, const float* __restrict__ b2,
        const float* __restrict__ W3, const float* __restrict__ b3,
        float* __restrict__ out, int N)
{
    __shared__ __align__(16) float    W1s[8][128];        // 4 KB  rows 0..6 = W1, row 7 = b1
    __shared__ __align__(16) _Float16 W2f[8][4][64][8];   // 32 KB canonical b-frags
    __shared__ __align__(16) float    W3s[128][4];        // 2 KB  straight copy
    __shared__ __align__(16) _Float16 scratch[4][64][40]; // 20 KB per-wave slice (h1 per-ks, then h2 per-s)

    const int tid  = threadIdx.x;
    const int lane = tid & 63;
    const int w    = tid >> 6;
    const int l15  = tid & 15;
    const int quad = (tid >> 4) & 3;

    // ---------------- weight pre-pack (once per block) ----------------
    for (int f = tid; f < 1024; f += 256) {               // W1 + b1, fp32
        int j = f >> 7, c = f & 127;
        W1s[j][c] = (j < 7) ? W1[j * 128 + c] : b1[c];
    }
    for (int m = tid; m < 128 * 128; m += 256) {          // W2[k][n] -> canonical frag
        int k = m >> 7, n = m & 127;
        W2f[n >> 4][k >> 5][((k >> 3) & 3) * 16 + (n & 15)][k & 7] = (_Float16)W2[m];
    }
    for (int f = tid; f < 512; f += 256)                  // W3 straight, fp32
        ((float*)W3s)[f] = W3[f];

    float b2r[8];
#pragma unroll
    for (int nt = 0; nt < 8; ++nt) b2r[nt] = b2[nt * 16 + l15];
    const float b30 = b3[0], b31 = b3[1], b32 = b3[2], b33 = b3[3];
    __syncthreads();   // only barrier; main-loop LDS traffic is wave-private

    const int ntiles = (N + 255) >> 8;
    for (int tile = blockIdx.x; tile < ntiles; tile += (int)gridDim.x) {
        const int p = tile * 256 + tid;

        // ---------------- invariants + polar (fp32, unchanged from R2) ----------------
        float a, b, c, d;
        if (p < N) {
            const float4 f4 = *(const float4*)(F + 4ll * p);
            a = f4.x; b = f4.y; c = f4.z; d = f4.w;
        } else { a = 1.f; b = 0.f; c = 0.f; d = 1.f; }
        const float x1 = a + d, y1 = c - b, x2 = a - d, y2 = c + b;
        const float h1v = sqrtf(x1 * x1 + y1 * y1);
        const float h2v = sqrtf(x2 * x2 + y2 * y2);
        const float s1 = 0.5f * (h1v + h2v), s2 = 0.5f * (h1v - h2v);
        const float ir = 1.0f / h1v;
        const float Rc = x1 * ir, Rs = y1 * ir;
        float invv[8];
        invv[0] = s1 - 1.f;
        invv[1] = s2 - 1.f;
        invv[2] = a * a + c * c - 1.f;
        invv[3] = a * b + c * d;
        invv[4] = invv[3];
        invv[5] = b * b + d * d - 1.f;
        invv[6] = a * d - b * c - 1.f;
        invv[7] = 1.0f;

        // ---------------- layer 1 (VALU) + layer 2 (MFMA), per 32-ch chunk ----------------
        f32x4 acc2[8][4];   // [nt2][mt2]
#pragma unroll
        for (int nt2 = 0; nt2 < 8; ++nt2)
#pragma unroll
            for (int mt2 = 0; mt2 < 4; ++mt2) acc2[nt2][mt2] = (f32x4){0.f, 0.f, 0.f, 0.f};

        for (int ks = 0; ks < 4; ++ks) {
            // h1 channels ks*32 .. ks*32+31 for this thread's own point
#pragma unroll
            for (int co = 0; co < 32; co += 2) {
                const int c0 = ks * 32 + co;
                float h0 = 0.f, h1_ = 0.f;
#pragma unroll
                for (int j = 0; j < 8; ++j) {
                    h0  += invv[j] * W1s[j][c0];
                    h1_ += invv[j] * W1s[j][c0 + 1];
                }
                f16x2 pw;
                pw[0] = (_Float16)fmaxf(h0, 0.f);
                pw[1] = (_Float16)fmaxf(h1_, 0.f);
                *(f16x2*)(&scratch[w][lane][co]) = pw;
            }
            // canonical A-frags: A[m=l15][k=quad*8+j] = h1[pt=mt2*16+l15][ks*32+quad*8+j]
            f16x8 af[4];
#pragma unroll
            for (int mt2 = 0; mt2 < 4; ++mt2)
                af[mt2] = *(const f16x8*)(&scratch[w][mt2 * 16 + l15][quad * 8]);
#pragma unroll
            for (int nt2 = 0; nt2 < 8; ++nt2) {
                const f16x8 bf = *(const f16x8*)(&W2f[nt2][ks][lane][0]);
#pragma unroll
                for (int mt2 = 0; mt2 < 4; ++mt2)
                    acc2[nt2][mt2] = MFMA(af[mt2], bf, acc2[nt2][mt2]);
            }
        }

        // ---------------- bias+relu -> h2 slices, layer 3 (VALU) ----------------
        float xr0 = b30, xr1 = b31, xr2 = b32, xr3 = b33;
        for (int s = 0; s < 4; ++s) {
#pragma unroll
            for (int h = 0; h < 2; ++h) {
                const int nt2 = 2 * s + h;
                const float bb = b2r[nt2];
#pragma unroll
                for (int mt2 = 0; mt2 < 4; ++mt2)
#pragma unroll
                    for (int r = 0; r < 4; ++r)
                        scratch[w][mt2 * 16 + quad * 4 + r][h * 16 + l15] =
                            (_Float16)fmaxf(acc2[nt2][mt2][r] + bb, 0.f);
            }
#pragma unroll
            for (int cc = 0; cc < 32; ++cc) {
                const float hv = (float)scratch[w][lane][cc];
                const float4 wv = *(const float4*)(&W3s[s * 32 + cc][0]);
                xr0 += hv * wv.x; xr1 += hv * wv.y;
                xr2 += hv * wv.z; xr3 += hv * wv.w;
            }
        }

        // ---------------- epilogue: symmetrize -> R@x + F (fp32, unchanged) ----------------
        const float xm  = 0.5f * (xr1 + xr2);
        const float d00 = Rc * xr0 - Rs * xm;
        const float d01 = Rc * xm  - Rs * xr3;
        const float d10 = Rs * xr0 + Rc * xm;
        const float d11 = Rs * xm  + Rc * xr3;
        if (p < N) {
            float4 o;
            o.x = a + d00; o.y = b + d01; o.z = c + d10; o.w = d + d11;
            *(float4*)(out + 4ll * p) = o;
        }
    }
}

extern "C" void kernel_launch(void* const* d_in, const int* in_sizes, int n_in,
                              void* d_out, int out_size, void* d_ws, size_t ws_size,
                              hipStream_t stream) {
    const float* F  = (const float*)d_in[0];
    const float* W1 = (const float*)d_in[1];
    const float* b1 = (const float*)d_in[2];
    const float* W2 = (const float*)d_in[3];
    const float* b2 = (const float*)d_in[4];
    const float* W3 = (const float*)d_in[5];
    const float* b3 = (const float*)d_in[6];
    float* out = (float*)d_out;
    const int N = in_sizes[0] / 4;
    const int ntiles = (N + 255) / 256;
    const int grid = ntiles < 1024 ? ntiles : 1024;
    DeformationCorrector_78967268704761_kernel<<<grid, 256, 0, stream>>>(
        F, W1, b1, W2, b2, W3, b3, out, N);
}

// Round 5
// 144.931 us; speedup vs baseline: 2.1151x; 2.1151x over previous
//
#include <hip/hip_runtime.h>

typedef _Float16 f16x8 __attribute__((ext_vector_type(8)));
typedef _Float16 f16x2 __attribute__((ext_vector_type(2)));
typedef float    f32x4 __attribute__((ext_vector_type(4)));

#define MFMA(a, b, c) __builtin_amdgcn_mfma_f32_16x16x32_f16((a), (b), (c), 0, 0, 0)

__device__ inline f16x8 zero8() {
    f16x8 z;
#pragma unroll
    for (int i = 0; i < 8; ++i) z[i] = (_Float16)0.0f;
    return z;
}

// All fragment maps are the R3-verified canonical ones:
//   A-frag:  A[m = lane&15][k = (lane>>4)*8 + j]
//   B-frag:  B[k = (lane>>4)*8 + j][n = lane&15]
//   C/D   :  D[m = (lane>>4)*4 + r][n = lane&15]
// Single-variable change vs R4: __launch_bounds__(256,1) — R3 (PASS) used (256,1),
// R1/R2/R4 (all ~0.04-0.05 absmax) used (256,2). Testing the spill/AGPR-copy
// miscompile hypothesis at the 256-VGPR cap.
__global__ __launch_bounds__(256, 1)
void DeformationCorrector_78967268704761_kernel(
        const float* __restrict__ F,
        const float* __restrict__ W1, const float* __restrict__ b1,
        const float* __restrict__ W2, const float* __restrict__ b2,
        const float* __restrict__ W3, const float* __restrict__ b3,
        float* __restrict__ out, int N)
{
    __shared__ __align__(16) _Float16 W2f[8][4][64][8];   // 32 KB canonical b-frags (verified R3)
    __shared__ __align__(16) _Float16 W1f[8][16][8];      // 2 KB  layer1 B-frags, lanes<16 (k<8)
    __shared__ __align__(16) _Float16 W3c[4][16][8];      // 1 KB  layer3 B-frags, compacted n<4
    __shared__ __align__(16) _Float16 invL[256][8];       // 4 KB  per-point invariants
    __shared__ __align__(16) _Float16 scratch[4][64][40]; // 20 KB per-wave h slice (also xls alias)

    const int tid  = threadIdx.x;
    const int lane = tid & 63;
    const int w    = tid >> 6;
    const int l15  = tid & 15;
    const int quad = (tid >> 4) & 3;

    // ---------------- weight pre-pack (once per block) ----------------
    for (int m = tid; m < 128 * 128; m += 256) {          // W2[k][n] -> canonical frag (R3-verified)
        int k = m >> 7, n = m & 127;
        W2f[n >> 4][k >> 5][((k >> 3) & 3) * 16 + (n & 15)][k & 7] = (_Float16)W2[m];
    }
    for (int f = tid; f < 1024; f += 256) {               // W1 b-frags: B[k=j][n], k=7 -> b1
        int nt = f >> 7, n15 = (f >> 3) & 15, j = f & 7;
        W1f[nt][n15][j] = (_Float16)((j < 7) ? W1[j * 128 + nt * 16 + n15]
                                             : b1[nt * 16 + n15]);
    }
    for (int f = tid; f < 512; f += 256) {                // W3 b-frags canonical, lanes q*4+n
        int s = f >> 7, idx = (f >> 3) & 15, j = f & 7;
        int q = idx >> 2, n = idx & 3;
        W3c[s][idx][j] = (_Float16)W3[(s * 32 + q * 8 + j) * 4 + n];
    }
    float b2r[8];
#pragma unroll
    for (int nt = 0; nt < 8; ++nt) b2r[nt] = b2[nt * 16 + l15];
    const float b3v = (l15 < 4) ? b3[l15] : 0.f;
    __syncthreads();   // only barrier; all main-loop LDS traffic is wave-private

    const int ntiles = (N + 255) >> 8;
    for (int tile = blockIdx.x; tile < ntiles; tile += (int)gridDim.x) {
        const int p = tile * 256 + tid;

        // ---------------- invariants + polar (fp32, verified) ----------------
        float a, b, c, d;
        if (p < N) {
            const float4 f4 = *(const float4*)(F + 4ll * p);
            a = f4.x; b = f4.y; c = f4.z; d = f4.w;
        } else { a = 1.f; b = 0.f; c = 0.f; d = 1.f; }
        const float x1 = a + d, y1 = c - b, x2 = a - d, y2 = c + b;
        const float h1v = sqrtf(x1 * x1 + y1 * y1);
        const float h2v = sqrtf(x2 * x2 + y2 * y2);
        const float s1 = 0.5f * (h1v + h2v), s2 = 0.5f * (h1v - h2v);
        const float ir = 1.0f / h1v;
        const float Rc = x1 * ir, Rs = y1 * ir;
        f16x8 iv;
        iv[0] = (_Float16)(s1 - 1.f);
        iv[1] = (_Float16)(s2 - 1.f);
        iv[2] = (_Float16)(a * a + c * c - 1.f);
        const float i3 = a * b + c * d;
        iv[3] = (_Float16)i3;
        iv[4] = (_Float16)i3;
        iv[5] = (_Float16)(b * b + d * d - 1.f);
        iv[6] = (_Float16)(a * d - b * c - 1.f);
        iv[7] = (_Float16)1.0f;
        *(f16x8*)(&invL[tid][0]) = iv;

        // inv A-frags: A[m=l15][k=quad*8+j], nonzero only quad==0 (k<8)
        f16x8 binv[4];
#pragma unroll
        for (int mt = 0; mt < 4; ++mt)
            binv[mt] = (quad == 0) ? *(const f16x8*)(&invL[w * 64 + mt * 16 + l15][0])
                                   : zero8();

        // ---------------- layers 1+2 per 32-channel chunk ----------------
        f32x4 acc2[8][4];   // [nt2][mt2]
#pragma unroll
        for (int nt2 = 0; nt2 < 8; ++nt2)
#pragma unroll
            for (int mt2 = 0; mt2 < 4; ++mt2) acc2[nt2][mt2] = (f32x4){0.f, 0.f, 0.f, 0.f};

        for (int ks = 0; ks < 4; ++ks) {
            // layer-1 MFMA: h1[pt][ch] for ch in [ks*32, ks*32+32)
#pragma unroll
            for (int h = 0; h < 2; ++h) {
                const f16x8 bw1 = (lane < 16) ? *(const f16x8*)(&W1f[2 * ks + h][l15][0])
                                              : zero8();
#pragma unroll
                for (int mt = 0; mt < 4; ++mt) {
                    f32x4 cz = {0.f, 0.f, 0.f, 0.f};
                    const f32x4 cc = MFMA(binv[mt], bw1, cz);
                    // D[pt = mt*16+quad*4+r][ch_local = h*16+l15] -> relu -> scratch
#pragma unroll
                    for (int r = 0; r < 4; ++r)
                        scratch[w][mt * 16 + quad * 4 + r][h * 16 + l15] =
                            (_Float16)fmaxf(cc[r], 0.f);
                }
            }
            // layer-2: canonical a-frags from slice + canonical W2 b-frags
            f16x8 af[4];
#pragma unroll
            for (int mt2 = 0; mt2 < 4; ++mt2)
                af[mt2] = *(const f16x8*)(&scratch[w][mt2 * 16 + l15][quad * 8]);
#pragma unroll
            for (int nt2 = 0; nt2 < 8; ++nt2) {
                const f16x8 bf = *(const f16x8*)(&W2f[nt2][ks][lane][0]);
#pragma unroll
                for (int mt2 = 0; mt2 < 4; ++mt2)
                    acc2[nt2][mt2] = MFMA(af[mt2], bf, acc2[nt2][mt2]);
            }
        }

        // ---------------- layer 3 per 32-channel chunk (MFMA) ----------------
        f32x4 acc3[4];
#pragma unroll
        for (int mt2 = 0; mt2 < 4; ++mt2) acc3[mt2] = (f32x4){0.f, 0.f, 0.f, 0.f};

#pragma unroll
        for (int s = 0; s < 4; ++s) {
#pragma unroll
            for (int h = 0; h < 2; ++h) {
                const int nt2 = 2 * s + h;
                const float bb = b2r[nt2];
#pragma unroll
                for (int mt2 = 0; mt2 < 4; ++mt2)
#pragma unroll
                    for (int r = 0; r < 4; ++r)
                        scratch[w][mt2 * 16 + quad * 4 + r][h * 16 + l15] =
                            (_Float16)fmaxf(acc2[nt2][mt2][r] + bb, 0.f);
            }
            const f16x8 bw3 = (l15 < 4) ? *(const f16x8*)(&W3c[s][quad * 4 + l15][0])
                                        : zero8();
#pragma unroll
            for (int mt2 = 0; mt2 < 4; ++mt2) {
                const f16x8 ah = *(const f16x8*)(&scratch[w][mt2 * 16 + l15][quad * 8]);
                acc3[mt2] = MFMA(ah, bw3, acc3[mt2]);
            }
        }

        // ---------------- epilogue: x via scratch alias -> R@x + F ----------------
        float* xf = (float*)(&scratch[w][0][0]);   // 1 KB of the 5 KB wave slice
#pragma unroll
        for (int mt2 = 0; mt2 < 4; ++mt2)
#pragma unroll
            for (int r = 0; r < 4; ++r)
                if (l15 < 4)
                    xf[(mt2 * 16 + quad * 4 + r) * 4 + l15] = acc3[mt2][r] + b3v;

        const float4 xv = *(const float4*)(&xf[lane * 4]);
        const float xm  = 0.5f * (xv.y + xv.z);
        const float d00 = Rc * xv.x - Rs * xm;
        const float d01 = Rc * xm   - Rs * xv.w;
        const float d10 = Rs * xv.x + Rc * xm;
        const float d11 = Rs * xm   + Rc * xv.w;
        if (p < N) {
            float4 o;
            o.x = a + d00; o.y = b + d01; o.z = c + d10; o.w = d + d11;
            *(float4*)(out + 4ll * p) = o;
        }
    }
}

extern "C" void kernel_launch(void* const* d_in, const int* in_sizes, int n_in,
                              void* d_out, int out_size, void* d_ws, size_t ws_size,
                              hipStream_t stream) {
    const float* F  = (const float*)d_in[0];
    const float* W1 = (const float*)d_in[1];
    const float* b1 = (const float*)d_in[2];
    const float* W2 = (const float*)d_in[3];
    const float* b2 = (const float*)d_in[4];
    const float* W3 = (const float*)d_in[5];
    const float* b3 = (const float*)d_in[6];
    float* out = (float*)d_out;
    const int N = in_sizes[0] / 4;
    const int ntiles = (N + 255) / 256;
    const int grid = ntiles < 1024 ? ntiles : 1024;
    DeformationCorrector_78967268704761_kernel<<<grid, 256, 0, stream>>>(
        F, W1, b1, W2, b2, W3, b3, out, N);
}